// Round 1
// baseline (2104.096 us; speedup 1.0000x reference)
//
#include <hip/hip_runtime.h>
#include <stdint.h>
#include <math.h>

#define SB 256
#define SI 8
#define SCHUNK (SB*SI)

__constant__ int c_tri[16][6] = {
  {-1,-1,-1,-1,-1,-1},{1,0,2,-1,-1,-1},{4,0,3,-1,-1,-1},{1,4,2,1,3,4},
  {3,1,5,-1,-1,-1},{2,3,0,2,5,3},{1,4,0,1,5,4},{4,2,5,-1,-1,-1},
  {4,5,2,-1,-1,-1},{4,1,0,4,5,1},{3,2,0,3,5,2},{1,3,5,-1,-1,-1},
  {4,1,2,4,3,1},{3,0,4,-1,-1,-1},{2,0,1,-1,-1,-1},{-1,-1,-1,-1,-1,-1}};
__constant__ int c_ntri[16] = {0,1,1,2,1,2,2,1,1,2,2,1,2,1,1,0};
__constant__ int c_ea[6] = {0,0,0,1,1,2};
__constant__ int c_eb[6] = {1,2,3,2,3,3};

// ---------------- classify tets + count crossing edges per lo-bucket ----------
__global__ void k_classify(const int4* __restrict__ tet, const float* __restrict__ sdf,
                           uint8_t* __restrict__ tetidx, int* __restrict__ bucketCnt, int nt) {
  int t = blockIdx.x * blockDim.x + threadIdx.x;
  if (t >= nt) return;
  int4 v = tet[t];
  int ids[4] = {v.x, v.y, v.z, v.w};
  int bits = 0;
#pragma unroll
  for (int i = 0; i < 4; i++) bits |= (sdf[ids[i]] > 0.0f) ? (1 << i) : 0;
  tetidx[t] = (uint8_t)bits;
  if (c_ntri[bits] == 0) return;
#pragma unroll
  for (int e = 0; e < 6; e++) {
    int a = c_ea[e], b = c_eb[e];
    if ((((bits >> a) ^ (bits >> b)) & 1) == 0) continue;
    int va = ids[a], vb = ids[b];
    int lo = va < vb ? va : vb;
    atomicAdd(&bucketCnt[lo], 1);
  }
}

// ---------------- block exclusive scans -------------------------------------
__device__ inline unsigned long long blkExclU64(unsigned long long val, unsigned long long* sh) {
  int tid = threadIdx.x;
  sh[tid] = val; __syncthreads();
  for (int st = 1; st < SB; st <<= 1) {
    unsigned long long add = (tid >= st) ? sh[tid - st] : 0ull;
    __syncthreads();
    sh[tid] += add;
    __syncthreads();
  }
  return sh[tid] - val;
}
__device__ inline int blkExclI32(int val, int* sh) {
  int tid = threadIdx.x;
  sh[tid] = val; __syncthreads();
  for (int st = 1; st < SB; st <<= 1) {
    int add = (tid >= st) ? sh[tid - st] : 0;
    __syncthreads();
    sh[tid] += add;
    __syncthreads();
  }
  return sh[tid] - val;
}

// tet scan: value = (ntri==1) | (ntri==2)<<32
__global__ void k_tetscan1(const uint8_t* __restrict__ tetidx, unsigned long long* __restrict__ bt, int n) {
  __shared__ unsigned long long sh[SB];
  int base = blockIdx.x * SCHUNK + threadIdx.x * SI;
  unsigned long long s = 0;
  for (int k = 0; k < SI; k++) {
    int i = base + k;
    if (i < n) {
      int nt3 = c_ntri[tetidx[i]];
      s += (nt3 == 1 ? 1ull : 0ull) + (nt3 == 2 ? (1ull << 32) : 0ull);
    }
  }
  sh[threadIdx.x] = s; __syncthreads();
  for (int st = SB / 2; st > 0; st >>= 1) {
    if (threadIdx.x < st) sh[threadIdx.x] += sh[threadIdx.x + st];
    __syncthreads();
  }
  if (threadIdx.x == 0) bt[blockIdx.x] = sh[0];
}
__global__ void k_scan2_u64(unsigned long long* bt, int nb, int* scal, int slotLo, int slotHi) {
  unsigned long long run = 0;
  for (int i = 0; i < nb; i++) { unsigned long long v = bt[i]; bt[i] = run; run += v; }
  scal[slotLo] = (int)(run & 0xffffffffull);
  scal[slotHi] = (int)(run >> 32);
}
__global__ void k_tetscan3(const uint8_t* __restrict__ tetidx, const unsigned long long* __restrict__ bt,
                           unsigned long long* __restrict__ tetRank, int n) {
  __shared__ unsigned long long sh[SB];
  int base = blockIdx.x * SCHUNK + threadIdx.x * SI;
  unsigned long long vals[SI];
  unsigned long long s = 0;
  for (int k = 0; k < SI; k++) {
    int i = base + k;
    unsigned long long v = 0;
    if (i < n) {
      int nt3 = c_ntri[tetidx[i]];
      v = (nt3 == 1 ? 1ull : 0ull) + (nt3 == 2 ? (1ull << 32) : 0ull);
    }
    vals[k] = s; s += v;
  }
  unsigned long long thrOff = blkExclU64(s, sh);
  unsigned long long off = bt[blockIdx.x] + thrOff;
  for (int k = 0; k < SI; k++) {
    int i = base + k;
    if (i < n) tetRank[i] = off + vals[k];
  }
}

__global__ void k_i32scan1(const int* __restrict__ src, int* __restrict__ bt, int n) {
  __shared__ int sh[SB];
  int base = blockIdx.x * SCHUNK + threadIdx.x * SI;
  int s = 0;
  for (int k = 0; k < SI; k++) { int i = base + k; if (i < n) s += src[i]; }
  sh[threadIdx.x] = s; __syncthreads();
  for (int st = SB / 2; st > 0; st >>= 1) {
    if (threadIdx.x < st) sh[threadIdx.x] += sh[threadIdx.x + st];
    __syncthreads();
  }
  if (threadIdx.x == 0) bt[blockIdx.x] = sh[0];
}
__global__ void k_scan2_i32(int* bt, int nb, int* scal, int slot) {
  int run = 0;
  for (int i = 0; i < nb; i++) { int v = bt[i]; bt[i] = run; run += v; }
  scal[slot] = run;
}
__global__ void k_i32scan3(const int* __restrict__ src, const int* __restrict__ bt,
                           int* __restrict__ dst, int* __restrict__ dst2, int n) {
  __shared__ int sh[SB];
  int base = blockIdx.x * SCHUNK + threadIdx.x * SI;
  int vals[SI];
  int s = 0;
  for (int k = 0; k < SI; k++) {
    int i = base + k;
    int v = (i < n) ? src[i] : 0;
    vals[k] = s; s += v;
  }
  int thrOff = blkExclI32(s, sh);
  int off = bt[blockIdx.x] + thrOff;
  for (int k = 0; k < SI; k++) {
    int i = base + k;
    if (i < n) {
      int val = off + vals[k];
      dst[i] = val;
      if (dst2) dst2[i] = val;
    }
  }
}

// ---------------- scatter crossing-edge occurrences into lo-buckets ----------
__global__ void k_scatter(const int4* __restrict__ tet, const uint8_t* __restrict__ tetidx,
                          int* __restrict__ bucketCur, unsigned long long* __restrict__ edges, int nt) {
  int t = blockIdx.x * blockDim.x + threadIdx.x;
  if (t >= nt) return;
  int bits = tetidx[t];
  if (c_ntri[bits] == 0) return;
  int4 v = tet[t];
  int ids[4] = {v.x, v.y, v.z, v.w};
#pragma unroll
  for (int e = 0; e < 6; e++) {
    int a = c_ea[e], b = c_eb[e];
    if ((((bits >> a) ^ (bits >> b)) & 1) == 0) continue;
    int va = ids[a], vb = ids[b];
    int lo = va < vb ? va : vb;
    int hi = va < vb ? vb : va;
    int p = atomicAdd(&bucketCur[lo], 1);
    edges[p] = ((unsigned long long)(unsigned)hi << 24) | (unsigned)(t * 6 + e);
  }
}

// ---------------- per-bucket sort (by hi,slot) + unique count ----------------
__global__ void k_sortcnt(const int* __restrict__ bucketOff, const int* __restrict__ bucketCnt,
                          unsigned long long* __restrict__ edges, int* __restrict__ uniqueCnt, int nv) {
  int v = blockIdx.x * blockDim.x + threadIdx.x;
  if (v >= nv) return;
  int n = bucketCnt[v];
  if (n == 0) { uniqueCnt[v] = 0; return; }
  unsigned long long* a = edges + bucketOff[v];
  for (int j = 1; j < n; j++) {
    unsigned long long key = a[j];
    int i = j - 1;
    while (i >= 0 && a[i] > key) { a[i + 1] = a[i]; i--; }
    a[i + 1] = key;
  }
  int u = 1;
  for (int j = 1; j < n; j++) u += ((a[j] >> 24) != (a[j - 1] >> 24)) ? 1 : 0;
  uniqueCnt[v] = u;
}

// ---------------- output offsets -------------------------------------------
// scal: 0=M1 1=M2 2=totSlots 3=E 4=facesOff 5=uvsOff 6=uvidxOff
__global__ void k_offsets(int* scal, int uvsElems) {
  int M1 = scal[0], M2 = scal[1], E = scal[3];
  int F = M1 + 2 * M2;
  scal[4] = 3 * E;
  scal[5] = 3 * E + 3 * F;
  scal[6] = scal[5] + uvsElems;
}

// ---------------- assign ranks, write verts + faces --------------------------
__global__ void k_emit(const int* __restrict__ bucketOff, const int* __restrict__ bucketCnt,
                       const unsigned long long* __restrict__ edges, const int* __restrict__ uniqueOff,
                       const uint8_t* __restrict__ tetidx, const unsigned long long* __restrict__ tetRank,
                       const float* __restrict__ pos, const float* __restrict__ sdf,
                       const int* __restrict__ scal, float* __restrict__ out, int nv) {
  int v = blockIdx.x * blockDim.x + threadIdx.x;
  if (v >= nv) return;
  int n = bucketCnt[v];
  if (n == 0) return;
  int off = bucketOff[v];
  int M1 = scal[0];
  int facesOff = scal[4];
  int r = uniqueOff[v] - 1;
  int prevHi = -1;
  float s0 = sdf[v];
  float p0x = pos[3 * v], p0y = pos[3 * v + 1], p0z = pos[3 * v + 2];
  for (int j = 0; j < n; j++) {
    unsigned long long key = edges[off + j];
    int hi = (int)(key >> 24);
    int slot = (int)(key & 0xffffffu);
    if (hi != prevHi) {
      prevHi = hi;
      r++;
      float s1 = sdf[hi];
      float ns1 = -s1;
      float denom = s0 + ns1;          // matches reference s.sum(1)
      float w0 = ns1 / denom;
      float w1 = s0 / denom;
      out[3 * r + 0] = p0x * w0 + pos[3 * hi + 0] * w1;
      out[3 * r + 1] = p0y * w0 + pos[3 * hi + 1] * w1;
      out[3 * r + 2] = p0z * w0 + pos[3 * hi + 2] * w1;
    }
    int t = slot / 6, e = slot - 6 * (slot / 6);
    int ti = tetidx[t];
    int nt3 = c_ntri[ti];
    unsigned long long pk = tetRank[t];
    if (nt3 == 1) {
      int row = (int)(pk & 0xffffffffull);
#pragma unroll
      for (int p = 0; p < 3; p++)
        if (c_tri[ti][p] == e) out[facesOff + row * 3 + p] = (float)r;
    } else {
      int base = M1 + 2 * (int)(pk >> 32);
#pragma unroll
      for (int p = 0; p < 6; p++)
        if (c_tri[ti][p] == e) out[facesOff + base * 3 + p] = (float)r;
    }
  }
}

// ---------------- uv_idx -----------------------------------------------------
__global__ void k_uvidx(const uint8_t* __restrict__ tetidx, const unsigned long long* __restrict__ tetRank,
                        const int* __restrict__ scal, float* __restrict__ out, int nt) {
  int t = blockIdx.x * blockDim.x + threadIdx.x;
  if (t >= nt) return;
  int ti = tetidx[t];
  int nt3 = c_ntri[ti];
  if (nt3 == 0) return;
  int M1 = scal[0];
  int uvidxOff = scal[6];
  unsigned long long pk = tetRank[t];
  if (nt3 == 1) {
    int row = (int)(pk & 0xffffffffull);
    float* o = out + uvidxOff + (size_t)row * 3;
    o[0] = (float)(4 * t); o[1] = (float)(4 * t + 1); o[2] = (float)(4 * t + 2);
  } else {
    int row = M1 + 2 * (int)(pk >> 32);
    float* o = out + uvidxOff + (size_t)row * 3;
    o[0] = (float)(4 * t); o[1] = (float)(4 * t + 1); o[2] = (float)(4 * t + 2);
    o[3] = (float)(4 * t); o[4] = (float)(4 * t + 2); o[5] = (float)(4 * t + 3);
  }
}

// ---------------- uvs --------------------------------------------------------
__global__ void k_uvs(const int* __restrict__ scal, float* __restrict__ out, int N) {
  int i = blockIdx.x * blockDim.x + threadIdx.x;
  int total = N * N;
  if (i >= total) return;
  int ty = i / N, tx = i - ty * N;
  float x = (float)tx / (float)N;
  float y = (float)ty / (float)N;
  float pad = (float)(0.9 / (double)N);
  float* o = out + scal[5] + (size_t)i * 8;
  o[0] = x;       o[1] = y;
  o[2] = x + pad; o[3] = y;
  o[4] = x + pad; o[5] = y + pad;
  o[6] = x;       o[7] = y + pad;
}

extern "C" void kernel_launch(void* const* d_in, const int* in_sizes, int n_in,
                              void* d_out, int out_size, void* d_ws, size_t ws_size,
                              hipStream_t stream) {
  const float* pos = (const float*)d_in[0];
  const float* sdf = (const float*)d_in[1];
  const int* tet = (const int*)d_in[2];
  int nv = in_sizes[1];
  int nt = in_sizes[2] / 4;

  // workspace layout (256B aligned slices)
  char* w = (char*)d_ws;
  size_t off = 0;
  auto A = [&](size_t bytes) -> char* {
    off = (off + 255) & ~(size_t)255;
    char* p = w + off;
    off += bytes;
    return p;
  };
  int* scal = (int*)A(64 * sizeof(int));
  uint8_t* tetidx = (uint8_t*)A((size_t)nt);
  unsigned long long* tetRank = (unsigned long long*)A((size_t)nt * 8);
  int* bucketCnt = (int*)A((size_t)nv * 4);
  int* bucketOff = (int*)A((size_t)nv * 4);
  int* bucketCur = (int*)A((size_t)nv * 4);
  int* uniqueCnt = (int*)A((size_t)nv * 4);
  int* uniqueOff = (int*)A((size_t)nv * 4);
  unsigned long long* blockTotU = (unsigned long long*)A(8 * 4096);
  int* blockTotI = (int*)A(4 * 4096);
  unsigned long long* edges = (unsigned long long*)A((size_t)nt * 4 * 8); // <=4 crossing edges per tet

  hipMemsetAsync(bucketCnt, 0, (size_t)nv * 4, stream);

  int nb_t = (nt + SCHUNK - 1) / SCHUNK;
  int nb_v = (nv + SCHUNK - 1) / SCHUNK;

  k_classify<<<(nt + 255) / 256, 256, 0, stream>>>((const int4*)tet, sdf, tetidx, bucketCnt, nt);

  k_tetscan1<<<nb_t, SB, 0, stream>>>(tetidx, blockTotU, nt);
  k_scan2_u64<<<1, 1, 0, stream>>>(blockTotU, nb_t, scal, 0, 1);
  k_tetscan3<<<nb_t, SB, 0, stream>>>(tetidx, blockTotU, tetRank, nt);

  k_i32scan1<<<nb_v, SB, 0, stream>>>(bucketCnt, blockTotI, nv);
  k_scan2_i32<<<1, 1, 0, stream>>>(blockTotI, nb_v, scal, 2);
  k_i32scan3<<<nb_v, SB, 0, stream>>>(bucketCnt, blockTotI, bucketOff, bucketCur, nv);

  k_scatter<<<(nt + 255) / 256, 256, 0, stream>>>((const int4*)tet, tetidx, bucketCur, edges, nt);
  k_sortcnt<<<(nv + 255) / 256, 256, 0, stream>>>(bucketOff, bucketCnt, edges, uniqueCnt, nv);

  k_i32scan1<<<nb_v, SB, 0, stream>>>(uniqueCnt, blockTotI, nv);
  k_scan2_i32<<<1, 1, 0, stream>>>(blockTotI, nb_v, scal, 3);
  k_i32scan3<<<nb_v, SB, 0, stream>>>(uniqueCnt, blockTotI, uniqueOff, (int*)nullptr, nv);

  long long maxidx = (long long)nt * 2;
  int N = (int)ceil(sqrt((double)((maxidx + 1) / 2)));
  int uvsElems = N * N * 8;

  k_offsets<<<1, 1, 0, stream>>>(scal, uvsElems);
  k_emit<<<(nv + 255) / 256, 256, 0, stream>>>(bucketOff, bucketCnt, edges, uniqueOff, tetidx,
                                               tetRank, pos, sdf, scal, (float*)d_out, nv);
  k_uvidx<<<(nt + 255) / 256, 256, 0, stream>>>(tetidx, tetRank, scal, (float*)d_out, nt);
  k_uvs<<<(N * N + 255) / 256, 256, 0, stream>>>(scal, (float*)d_out, N);
}

// Round 2
// 1648.849 us; speedup vs baseline: 1.2761x; 1.2761x over previous
//
#include <hip/hip_runtime.h>
#include <stdint.h>
#include <math.h>

#define SB 256
#define SI 8
#define SCHUNK (SB*SI)

__constant__ int c_tri[16][6] = {
  {-1,-1,-1,-1,-1,-1},{1,0,2,-1,-1,-1},{4,0,3,-1,-1,-1},{1,4,2,1,3,4},
  {3,1,5,-1,-1,-1},{2,3,0,2,5,3},{1,4,0,1,5,4},{4,2,5,-1,-1,-1},
  {4,5,2,-1,-1,-1},{4,1,0,4,5,1},{3,2,0,3,5,2},{1,3,5,-1,-1,-1},
  {4,1,2,4,3,1},{3,0,4,-1,-1,-1},{2,0,1,-1,-1,-1},{-1,-1,-1,-1,-1,-1}};
__constant__ int c_ntri[16] = {0,1,1,2,1,2,2,1,1,2,2,1,2,1,1,0};
__constant__ int c_ea[6] = {0,0,0,1,1,2};
__constant__ int c_eb[6] = {1,2,3,2,3,3};

// ---------------- classify tets + count crossing edges per lo-bucket ----------
__global__ void k_classify(const int4* __restrict__ tet, const float* __restrict__ sdf,
                           uint8_t* __restrict__ tetidx, int* __restrict__ bucketCnt, int nt) {
  int t = blockIdx.x * blockDim.x + threadIdx.x;
  if (t >= nt) return;
  int4 v = tet[t];
  int ids[4] = {v.x, v.y, v.z, v.w};
  int bits = 0;
#pragma unroll
  for (int i = 0; i < 4; i++) bits |= (sdf[ids[i]] > 0.0f) ? (1 << i) : 0;
  tetidx[t] = (uint8_t)bits;
  if (c_ntri[bits] == 0) return;
#pragma unroll
  for (int e = 0; e < 6; e++) {
    int a = c_ea[e], b = c_eb[e];
    if ((((bits >> a) ^ (bits >> b)) & 1) == 0) continue;
    int va = ids[a], vb = ids[b];
    int lo = va < vb ? va : vb;
    atomicAdd(&bucketCnt[lo], 1);
  }
}

// ---------------- block exclusive scans -------------------------------------
__device__ inline unsigned long long blkExclU64(unsigned long long val, unsigned long long* sh) {
  int tid = threadIdx.x;
  sh[tid] = val; __syncthreads();
  for (int st = 1; st < SB; st <<= 1) {
    unsigned long long add = (tid >= st) ? sh[tid - st] : 0ull;
    __syncthreads();
    sh[tid] += add;
    __syncthreads();
  }
  return sh[tid] - val;
}
__device__ inline int blkExclI32(int val, int* sh) {
  int tid = threadIdx.x;
  sh[tid] = val; __syncthreads();
  for (int st = 1; st < SB; st <<= 1) {
    int add = (tid >= st) ? sh[tid - st] : 0;
    __syncthreads();
    sh[tid] += add;
    __syncthreads();
  }
  return sh[tid] - val;
}

// tet scan: value = (ntri==1) | (ntri==2)<<32
__global__ void k_tetscan1(const uint8_t* __restrict__ tetidx, unsigned long long* __restrict__ bt, int n) {
  __shared__ unsigned long long sh[SB];
  int base = blockIdx.x * SCHUNK + threadIdx.x * SI;
  unsigned long long s = 0;
  for (int k = 0; k < SI; k++) {
    int i = base + k;
    if (i < n) {
      int nt3 = c_ntri[tetidx[i]];
      s += (nt3 == 1 ? 1ull : 0ull) + (nt3 == 2 ? (1ull << 32) : 0ull);
    }
  }
  sh[threadIdx.x] = s; __syncthreads();
  for (int st = SB / 2; st > 0; st >>= 1) {
    if (threadIdx.x < st) sh[threadIdx.x] += sh[threadIdx.x + st];
    __syncthreads();
  }
  if (threadIdx.x == 0) bt[blockIdx.x] = sh[0];
}

// single-block parallel scan over block totals (u64), replaces serial loop
__global__ void k_scanblk_u64(unsigned long long* __restrict__ bt, int nb,
                              int* __restrict__ scal, int slotLo, int slotHi) {
  __shared__ unsigned long long sh[SB];
  __shared__ unsigned long long carrySh;
  if (threadIdx.x == 0) carrySh = 0;
  __syncthreads();
  for (int base = 0; base < nb; base += SB) {
    int i = base + threadIdx.x;
    unsigned long long v = (i < nb) ? bt[i] : 0ull;
    unsigned long long ex = blkExclU64(v, sh);
    unsigned long long carry = carrySh;
    if (i < nb) bt[i] = carry + ex;
    __syncthreads();
    if (threadIdx.x == SB - 1) carrySh = carry + ex + v;
    __syncthreads();
  }
  if (threadIdx.x == 0) {
    scal[slotLo] = (int)(carrySh & 0xffffffffull);
    scal[slotHi] = (int)(carrySh >> 32);
  }
}

__global__ void k_tetscan3(const uint8_t* __restrict__ tetidx, const unsigned long long* __restrict__ bt,
                           unsigned long long* __restrict__ tetRank, int n) {
  __shared__ unsigned long long sh[SB];
  int base = blockIdx.x * SCHUNK + threadIdx.x * SI;
  unsigned long long vals[SI];
  unsigned long long s = 0;
  for (int k = 0; k < SI; k++) {
    int i = base + k;
    unsigned long long v = 0;
    if (i < n) {
      int nt3 = c_ntri[tetidx[i]];
      v = (nt3 == 1 ? 1ull : 0ull) + (nt3 == 2 ? (1ull << 32) : 0ull);
    }
    vals[k] = s; s += v;
  }
  unsigned long long thrOff = blkExclU64(s, sh);
  unsigned long long off = bt[blockIdx.x] + thrOff;
  for (int k = 0; k < SI; k++) {
    int i = base + k;
    if (i < n) tetRank[i] = off + vals[k];
  }
}

__global__ void k_i32scan1(const int* __restrict__ src, int* __restrict__ bt, int n) {
  __shared__ int sh[SB];
  int base = blockIdx.x * SCHUNK + threadIdx.x * SI;
  int s = 0;
  for (int k = 0; k < SI; k++) { int i = base + k; if (i < n) s += src[i]; }
  sh[threadIdx.x] = s; __syncthreads();
  for (int st = SB / 2; st > 0; st >>= 1) {
    if (threadIdx.x < st) sh[threadIdx.x] += sh[threadIdx.x + st];
    __syncthreads();
  }
  if (threadIdx.x == 0) bt[blockIdx.x] = sh[0];
}

// single-block parallel scan over block totals (i32)
__global__ void k_scanblk_i32(int* __restrict__ bt, int nb, int* __restrict__ scal, int slot) {
  __shared__ int sh[SB];
  __shared__ int carrySh;
  if (threadIdx.x == 0) carrySh = 0;
  __syncthreads();
  for (int base = 0; base < nb; base += SB) {
    int i = base + threadIdx.x;
    int v = (i < nb) ? bt[i] : 0;
    int ex = blkExclI32(v, sh);
    int carry = carrySh;
    if (i < nb) bt[i] = carry + ex;
    __syncthreads();
    if (threadIdx.x == SB - 1) carrySh = carry + ex + v;
    __syncthreads();
  }
  if (threadIdx.x == 0) scal[slot] = carrySh;
}

__global__ void k_i32scan3(const int* __restrict__ src, const int* __restrict__ bt,
                           int* __restrict__ dst, int* __restrict__ dst2, int n) {
  __shared__ int sh[SB];
  int base = blockIdx.x * SCHUNK + threadIdx.x * SI;
  int vals[SI];
  int s = 0;
  for (int k = 0; k < SI; k++) {
    int i = base + k;
    int v = (i < n) ? src[i] : 0;
    vals[k] = s; s += v;
  }
  int thrOff = blkExclI32(s, sh);
  int off = bt[blockIdx.x] + thrOff;
  for (int k = 0; k < SI; k++) {
    int i = base + k;
    if (i < n) {
      int val = off + vals[k];
      dst[i] = val;
      if (dst2) dst2[i] = val;
    }
  }
}

// ---------------- scatter crossing-edge occurrences into lo-buckets ----------
// key layout: [63:44]=hi  [43:20]=pos1 (face elem idx, rel. to faces base)
//             [19:17]=delta(pos2-pos1)  [16]=has2  [15:0]=0
// Face positions precomputed HERE (per-tet coalesced reads of tetidx/tetRank)
// so k_emit never touches tetidx/tetRank (was 2x 64B random lines per occ).
__global__ void k_scatter(const int4* __restrict__ tet, const uint8_t* __restrict__ tetidx,
                          const unsigned long long* __restrict__ tetRank, const int* __restrict__ scal,
                          int* __restrict__ bucketCur, unsigned long long* __restrict__ edges, int nt) {
  int t = blockIdx.x * blockDim.x + threadIdx.x;
  if (t >= nt) return;
  int bits = tetidx[t];
  int nt3 = c_ntri[bits];
  if (nt3 == 0) return;
  int4 v = tet[t];
  int ids[4] = {v.x, v.y, v.z, v.w};
  unsigned long long pk = tetRank[t];
  int M1 = scal[0];
  int rowElemBase = (nt3 == 1) ? 3 * (int)(pk & 0xffffffffull)
                               : 3 * M1 + 6 * (int)(pk >> 32);
  int npos = 3 * nt3;
#pragma unroll
  for (int e = 0; e < 6; e++) {
    int a = c_ea[e], b = c_eb[e];
    if ((((bits >> a) ^ (bits >> b)) & 1) == 0) continue;
    int va = ids[a], vb = ids[b];
    int lo = va < vb ? va : vb;
    int hi = va < vb ? vb : va;
    int p1 = -1, p2 = -1;
    for (int p = 0; p < npos; p++) {
      if (c_tri[bits][p] == e) { if (p1 < 0) p1 = p; else p2 = p; }
    }
    unsigned long long key = ((unsigned long long)(unsigned)hi << 44)
                           | ((unsigned long long)(unsigned)(rowElemBase + p1) << 20)
                           | ((p2 >= 0) ? (((unsigned long long)(p2 - p1) << 17) | (1ull << 16)) : 0ull);
    int pidx = atomicAdd(&bucketCur[lo], 1);
    edges[pidx] = key;
  }
}

// ---------------- per-bucket sort (by hi,payload) + unique count -------------
__global__ void k_sortcnt(const int* __restrict__ bucketOff, const int* __restrict__ bucketCnt,
                          unsigned long long* __restrict__ edges, int* __restrict__ uniqueCnt, int nv) {
  int v = blockIdx.x * blockDim.x + threadIdx.x;
  if (v >= nv) return;
  int n = bucketCnt[v];
  if (n == 0) { uniqueCnt[v] = 0; return; }
  unsigned long long* a = edges + bucketOff[v];
  for (int j = 1; j < n; j++) {
    unsigned long long key = a[j];
    int i = j - 1;
    while (i >= 0 && a[i] > key) { a[i + 1] = a[i]; i--; }
    a[i + 1] = key;
  }
  int u = 1;
  for (int j = 1; j < n; j++) u += ((a[j] >> 44) != (a[j - 1] >> 44)) ? 1 : 0;
  uniqueCnt[v] = u;
}

// ---------------- output offsets -------------------------------------------
// scal: 0=M1 1=M2 2=totSlots 3=E 4=facesOff 5=uvsOff 6=uvidxOff
__global__ void k_offsets(int* scal, int uvsElems) {
  int M1 = scal[0], M2 = scal[1], E = scal[3];
  int F = M1 + 2 * M2;
  scal[4] = 3 * E;
  scal[5] = 3 * E + 3 * F;
  scal[6] = scal[5] + uvsElems;
}

// ---------------- assign ranks, write verts + faces --------------------------
__global__ void k_emit(const int* __restrict__ bucketOff, const int* __restrict__ bucketCnt,
                       const unsigned long long* __restrict__ edges, const int* __restrict__ uniqueOff,
                       const float* __restrict__ pos, const float* __restrict__ sdf,
                       const int* __restrict__ scal, float* __restrict__ out, int nv) {
  int v = blockIdx.x * blockDim.x + threadIdx.x;
  if (v >= nv) return;
  int n = bucketCnt[v];
  if (n == 0) return;
  int off = bucketOff[v];
  int facesOff = scal[4];
  int r = uniqueOff[v] - 1;
  unsigned long long prevHi = ~0ull;
  float s0 = sdf[v];
  float p0x = pos[3 * v], p0y = pos[3 * v + 1], p0z = pos[3 * v + 2];
  for (int j = 0; j < n; j++) {
    unsigned long long key = edges[off + j];
    unsigned long long hi44 = key >> 44;
    if (hi44 != prevHi) {
      prevHi = hi44;
      r++;
      int hi = (int)hi44;
      float s1 = sdf[hi];
      float ns1 = -s1;
      float denom = s0 + ns1;          // matches reference s.sum(1)
      float w0 = ns1 / denom;
      float w1 = s0 / denom;
      out[3 * r + 0] = p0x * w0 + pos[3 * hi + 0] * w1;
      out[3 * r + 1] = p0y * w0 + pos[3 * hi + 1] * w1;
      out[3 * r + 2] = p0z * w0 + pos[3 * hi + 2] * w1;
    }
    int pos1 = (int)((key >> 20) & 0xffffffull);
    float fr = (float)r;
    out[facesOff + pos1] = fr;
    if ((key >> 16) & 1ull) {
      int delta = (int)((key >> 17) & 7ull);
      out[facesOff + pos1 + delta] = fr;
    }
  }
}

// ---------------- uv_idx -----------------------------------------------------
__global__ void k_uvidx(const uint8_t* __restrict__ tetidx, const unsigned long long* __restrict__ tetRank,
                        const int* __restrict__ scal, float* __restrict__ out, int nt) {
  int t = blockIdx.x * blockDim.x + threadIdx.x;
  if (t >= nt) return;
  int ti = tetidx[t];
  int nt3 = c_ntri[ti];
  if (nt3 == 0) return;
  int M1 = scal[0];
  int uvidxOff = scal[6];
  unsigned long long pk = tetRank[t];
  if (nt3 == 1) {
    int row = (int)(pk & 0xffffffffull);
    float* o = out + uvidxOff + (size_t)row * 3;
    o[0] = (float)(4 * t); o[1] = (float)(4 * t + 1); o[2] = (float)(4 * t + 2);
  } else {
    int row = M1 + 2 * (int)(pk >> 32);
    float* o = out + uvidxOff + (size_t)row * 3;
    o[0] = (float)(4 * t); o[1] = (float)(4 * t + 1); o[2] = (float)(4 * t + 2);
    o[3] = (float)(4 * t); o[4] = (float)(4 * t + 2); o[5] = (float)(4 * t + 3);
  }
}

// ---------------- uvs --------------------------------------------------------
__global__ void k_uvs(const int* __restrict__ scal, float* __restrict__ out, int N) {
  int i = blockIdx.x * blockDim.x + threadIdx.x;
  int total = N * N;
  if (i >= total) return;
  int ty = i / N, tx = i - ty * N;
  float x = (float)tx / (float)N;
  float y = (float)ty / (float)N;
  float pad = (float)(0.9 / (double)N);
  float* o = out + scal[5] + (size_t)i * 8;
  o[0] = x;       o[1] = y;
  o[2] = x + pad; o[3] = y;
  o[4] = x + pad; o[5] = y + pad;
  o[6] = x;       o[7] = y + pad;
}

extern "C" void kernel_launch(void* const* d_in, const int* in_sizes, int n_in,
                              void* d_out, int out_size, void* d_ws, size_t ws_size,
                              hipStream_t stream) {
  const float* pos = (const float*)d_in[0];
  const float* sdf = (const float*)d_in[1];
  const int* tet = (const int*)d_in[2];
  int nv = in_sizes[1];
  int nt = in_sizes[2] / 4;

  // workspace layout (256B aligned slices)
  char* w = (char*)d_ws;
  size_t off = 0;
  auto A = [&](size_t bytes) -> char* {
    off = (off + 255) & ~(size_t)255;
    char* p = w + off;
    off += bytes;
    return p;
  };
  int* scal = (int*)A(64 * sizeof(int));
  uint8_t* tetidx = (uint8_t*)A((size_t)nt);
  unsigned long long* tetRank = (unsigned long long*)A((size_t)nt * 8);
  int* bucketCnt = (int*)A((size_t)nv * 4);
  int* bucketOff = (int*)A((size_t)nv * 4);
  int* bucketCur = (int*)A((size_t)nv * 4);
  int* uniqueCnt = (int*)A((size_t)nv * 4);
  int* uniqueOff = (int*)A((size_t)nv * 4);
  unsigned long long* blockTotU = (unsigned long long*)A(8 * 4096);
  int* blockTotI = (int*)A(4 * 4096);
  unsigned long long* edges = (unsigned long long*)A((size_t)nt * 4 * 8); // <=4 crossing edges per tet

  hipMemsetAsync(bucketCnt, 0, (size_t)nv * 4, stream);

  int nb_t = (nt + SCHUNK - 1) / SCHUNK;
  int nb_v = (nv + SCHUNK - 1) / SCHUNK;

  k_classify<<<(nt + 255) / 256, 256, 0, stream>>>((const int4*)tet, sdf, tetidx, bucketCnt, nt);

  k_tetscan1<<<nb_t, SB, 0, stream>>>(tetidx, blockTotU, nt);
  k_scanblk_u64<<<1, SB, 0, stream>>>(blockTotU, nb_t, scal, 0, 1);
  k_tetscan3<<<nb_t, SB, 0, stream>>>(tetidx, blockTotU, tetRank, nt);

  k_i32scan1<<<nb_v, SB, 0, stream>>>(bucketCnt, blockTotI, nv);
  k_scanblk_i32<<<1, SB, 0, stream>>>(blockTotI, nb_v, scal, 2);
  k_i32scan3<<<nb_v, SB, 0, stream>>>(bucketCnt, blockTotI, bucketOff, bucketCur, nv);

  k_scatter<<<(nt + 255) / 256, 256, 0, stream>>>((const int4*)tet, tetidx, tetRank, scal,
                                                  bucketCur, edges, nt);
  k_sortcnt<<<(nv + 255) / 256, 256, 0, stream>>>(bucketOff, bucketCnt, edges, uniqueCnt, nv);

  k_i32scan1<<<nb_v, SB, 0, stream>>>(uniqueCnt, blockTotI, nv);
  k_scanblk_i32<<<1, SB, 0, stream>>>(blockTotI, nb_v, scal, 3);
  k_i32scan3<<<nb_v, SB, 0, stream>>>(uniqueCnt, blockTotI, uniqueOff, (int*)nullptr, nv);

  long long maxidx = (long long)nt * 2;
  int N = (int)ceil(sqrt((double)((maxidx + 1) / 2)));
  int uvsElems = N * N * 8;

  k_offsets<<<1, 1, 0, stream>>>(scal, uvsElems);
  k_emit<<<(nv + 255) / 256, 256, 0, stream>>>(bucketOff, bucketCnt, edges, uniqueOff,
                                               pos, sdf, scal, (float*)d_out, nv);
  k_uvidx<<<(nt + 255) / 256, 256, 0, stream>>>(tetidx, tetRank, scal, (float*)d_out, nt);
  k_uvs<<<(N * N + 255) / 256, 256, 0, stream>>>(scal, (float*)d_out, N);
}

// Round 3
// 1377.923 us; speedup vs baseline: 1.5270x; 1.1966x over previous
//
#include <hip/hip_runtime.h>
#include <stdint.h>
#include <math.h>

#define SB 256
#define SI 8
#define SCHUNK (SB*SI)

__constant__ int c_tri[16][6] = {
  {-1,-1,-1,-1,-1,-1},{1,0,2,-1,-1,-1},{4,0,3,-1,-1,-1},{1,4,2,1,3,4},
  {3,1,5,-1,-1,-1},{2,3,0,2,5,3},{1,4,0,1,5,4},{4,2,5,-1,-1,-1},
  {4,5,2,-1,-1,-1},{4,1,0,4,5,1},{3,2,0,3,5,2},{1,3,5,-1,-1,-1},
  {4,1,2,4,3,1},{3,0,4,-1,-1,-1},{2,0,1,-1,-1,-1},{-1,-1,-1,-1,-1,-1}};
__constant__ int c_ntri[16] = {0,1,1,2,1,2,2,1,1,2,2,1,2,1,1,0};
__constant__ int c_ea[6] = {0,0,0,1,1,2};
__constant__ int c_eb[6] = {1,2,3,2,3,3};

// ---------------- classify tets: occupancy bits + bucket count + slot stash --
// Stash (ushort4 per tet) holds the in-bucket index of each crossing edge
// (crossing-ordinal order). Scatter then needs NO atomics.
__global__ void k_classify(const int4* __restrict__ tet, const float* __restrict__ sdf,
                           uint8_t* __restrict__ tetidx, int* __restrict__ bucketCnt,
                           ushort4* __restrict__ stash, int nt) {
  int t = blockIdx.x * blockDim.x + threadIdx.x;
  if (t >= nt) return;
  int4 v = tet[t];
  int ids[4] = {v.x, v.y, v.z, v.w};
  int bits = 0;
#pragma unroll
  for (int i = 0; i < 4; i++) bits |= (sdf[ids[i]] > 0.0f) ? (1 << i) : 0;
  tetidx[t] = (uint8_t)bits;
  if (c_ntri[bits] == 0) return;
  unsigned short st[4] = {0, 0, 0, 0};
  int c = 0;
#pragma unroll
  for (int e = 0; e < 6; e++) {
    int a = c_ea[e], b = c_eb[e];
    if ((((bits >> a) ^ (bits >> b)) & 1) == 0) continue;
    int va = ids[a], vb = ids[b];
    int lo = va < vb ? va : vb;
    st[c++] = (unsigned short)atomicAdd(&bucketCnt[lo], 1);
  }
  stash[t] = make_ushort4(st[0], st[1], st[2], st[3]);
}

// ---------------- block exclusive scans -------------------------------------
__device__ inline unsigned long long blkExclU64(unsigned long long val, unsigned long long* sh) {
  int tid = threadIdx.x;
  sh[tid] = val; __syncthreads();
  for (int st = 1; st < SB; st <<= 1) {
    unsigned long long add = (tid >= st) ? sh[tid - st] : 0ull;
    __syncthreads();
    sh[tid] += add;
    __syncthreads();
  }
  return sh[tid] - val;
}
__device__ inline int blkExclI32(int val, int* sh) {
  int tid = threadIdx.x;
  sh[tid] = val; __syncthreads();
  for (int st = 1; st < SB; st <<= 1) {
    int add = (tid >= st) ? sh[tid - st] : 0;
    __syncthreads();
    sh[tid] += add;
    __syncthreads();
  }
  return sh[tid] - val;
}

// tet scan: value = (ntri==1) | (ntri==2)<<32
__global__ void k_tetscan1(const uint8_t* __restrict__ tetidx, unsigned long long* __restrict__ bt, int n) {
  __shared__ unsigned long long sh[SB];
  int base = blockIdx.x * SCHUNK + threadIdx.x * SI;
  unsigned long long s = 0;
  for (int k = 0; k < SI; k++) {
    int i = base + k;
    if (i < n) {
      int nt3 = c_ntri[tetidx[i]];
      s += (nt3 == 1 ? 1ull : 0ull) + (nt3 == 2 ? (1ull << 32) : 0ull);
    }
  }
  sh[threadIdx.x] = s; __syncthreads();
  for (int st = SB / 2; st > 0; st >>= 1) {
    if (threadIdx.x < st) sh[threadIdx.x] += sh[threadIdx.x + st];
    __syncthreads();
  }
  if (threadIdx.x == 0) bt[blockIdx.x] = sh[0];
}

__global__ void k_scanblk_u64(unsigned long long* __restrict__ bt, int nb,
                              int* __restrict__ scal, int slotLo, int slotHi) {
  __shared__ unsigned long long sh[SB];
  __shared__ unsigned long long carrySh;
  if (threadIdx.x == 0) carrySh = 0;
  __syncthreads();
  for (int base = 0; base < nb; base += SB) {
    int i = base + threadIdx.x;
    unsigned long long v = (i < nb) ? bt[i] : 0ull;
    unsigned long long ex = blkExclU64(v, sh);
    unsigned long long carry = carrySh;
    if (i < nb) bt[i] = carry + ex;
    __syncthreads();
    if (threadIdx.x == SB - 1) carrySh = carry + ex + v;
    __syncthreads();
  }
  if (threadIdx.x == 0) {
    scal[slotLo] = (int)(carrySh & 0xffffffffull);
    scal[slotHi] = (int)(carrySh >> 32);
  }
}

__global__ void k_tetscan3(const uint8_t* __restrict__ tetidx, const unsigned long long* __restrict__ bt,
                           unsigned long long* __restrict__ tetRank, int n) {
  __shared__ unsigned long long sh[SB];
  int base = blockIdx.x * SCHUNK + threadIdx.x * SI;
  unsigned long long vals[SI];
  unsigned long long s = 0;
  for (int k = 0; k < SI; k++) {
    int i = base + k;
    unsigned long long v = 0;
    if (i < n) {
      int nt3 = c_ntri[tetidx[i]];
      v = (nt3 == 1 ? 1ull : 0ull) + (nt3 == 2 ? (1ull << 32) : 0ull);
    }
    vals[k] = s; s += v;
  }
  unsigned long long thrOff = blkExclU64(s, sh);
  unsigned long long off = bt[blockIdx.x] + thrOff;
  for (int k = 0; k < SI; k++) {
    int i = base + k;
    if (i < n) tetRank[i] = off + vals[k];
  }
}

__global__ void k_i32scan1(const int* __restrict__ src, int* __restrict__ bt, int n) {
  __shared__ int sh[SB];
  int base = blockIdx.x * SCHUNK + threadIdx.x * SI;
  int s = 0;
  for (int k = 0; k < SI; k++) { int i = base + k; if (i < n) s += src[i]; }
  sh[threadIdx.x] = s; __syncthreads();
  for (int st = SB / 2; st > 0; st >>= 1) {
    if (threadIdx.x < st) sh[threadIdx.x] += sh[threadIdx.x + st];
    __syncthreads();
  }
  if (threadIdx.x == 0) bt[blockIdx.x] = sh[0];
}

__global__ void k_scanblk_i32(int* __restrict__ bt, int nb, int* __restrict__ scal, int slot) {
  __shared__ int sh[SB];
  __shared__ int carrySh;
  if (threadIdx.x == 0) carrySh = 0;
  __syncthreads();
  for (int base = 0; base < nb; base += SB) {
    int i = base + threadIdx.x;
    int v = (i < nb) ? bt[i] : 0;
    int ex = blkExclI32(v, sh);
    int carry = carrySh;
    if (i < nb) bt[i] = carry + ex;
    __syncthreads();
    if (threadIdx.x == SB - 1) carrySh = carry + ex + v;
    __syncthreads();
  }
  if (threadIdx.x == 0) scal[slot] = carrySh;
}

__global__ void k_i32scan3(const int* __restrict__ src, const int* __restrict__ bt,
                           int* __restrict__ dst, int n) {
  __shared__ int sh[SB];
  int base = blockIdx.x * SCHUNK + threadIdx.x * SI;
  int vals[SI];
  int s = 0;
  for (int k = 0; k < SI; k++) {
    int i = base + k;
    int v = (i < n) ? src[i] : 0;
    vals[k] = s; s += v;
  }
  int thrOff = blkExclI32(s, sh);
  int off = bt[blockIdx.x] + thrOff;
  for (int k = 0; k < SI; k++) {
    int i = base + k;
    if (i < n) dst[i] = off + vals[k];
  }
}

// ---------------- scatter (atomic-free) --------------------------------------
// key: [63:44]=hi [43:20]=pos1 (face elem idx) [19:17]=delta [16]=has2 [15:0]=origIdxInBucket
__global__ void k_scatter(const int4* __restrict__ tet, const uint8_t* __restrict__ tetidx,
                          const unsigned long long* __restrict__ tetRank, const int* __restrict__ scal,
                          const int* __restrict__ bucketOff, const ushort4* __restrict__ stash,
                          unsigned long long* __restrict__ edges, int nt) {
  int t = blockIdx.x * blockDim.x + threadIdx.x;
  if (t >= nt) return;
  int bits = tetidx[t];
  int nt3 = c_ntri[bits];
  if (nt3 == 0) return;
  int4 v = tet[t];
  int ids[4] = {v.x, v.y, v.z, v.w};
  unsigned long long pk = tetRank[t];
  int M1 = scal[0];
  int rowElemBase = (nt3 == 1) ? 3 * (int)(pk & 0xffffffffull)
                               : 3 * M1 + 6 * (int)(pk >> 32);
  ushort4 stv = stash[t];
  unsigned short sta[4] = {stv.x, stv.y, stv.z, stv.w};
  int npos = 3 * nt3;
  int c = 0;
#pragma unroll
  for (int e = 0; e < 6; e++) {
    int a = c_ea[e], b = c_eb[e];
    if ((((bits >> a) ^ (bits >> b)) & 1) == 0) continue;
    int va = ids[a], vb = ids[b];
    int lo = va < vb ? va : vb;
    int hi = va < vb ? vb : va;
    int p1 = -1, p2 = -1;
    for (int p = 0; p < npos; p++) {
      if (c_tri[bits][p] == e) { if (p1 < 0) p1 = p; else p2 = p; }
    }
    int orig = sta[c++];
    unsigned long long key = ((unsigned long long)(unsigned)hi << 44)
                           | ((unsigned long long)(unsigned)(rowElemBase + p1) << 20)
                           | ((p2 >= 0) ? (((unsigned long long)(p2 - p1) << 17) | (1ull << 16)) : 0ull)
                           | (unsigned long long)orig;
    edges[bucketOff[lo] + orig] = key;
  }
}

// ---------------- per-bucket sort + unique count -----------------------------
__global__ void k_sortcnt(const int* __restrict__ bucketOff, const int* __restrict__ bucketCnt,
                          unsigned long long* __restrict__ edges, int* __restrict__ uniqueCnt, int nv) {
  int v = blockIdx.x * blockDim.x + threadIdx.x;
  if (v >= nv) return;
  int n = bucketCnt[v];
  if (n == 0) { uniqueCnt[v] = 0; return; }
  unsigned long long* a = edges + bucketOff[v];
  for (int j = 1; j < n; j++) {
    unsigned long long key = a[j];
    int i = j - 1;
    while (i >= 0 && a[i] > key) { a[i + 1] = a[i]; i--; }
    a[i + 1] = key;
  }
  int u = 1;
  for (int j = 1; j < n; j++) u += ((a[j] >> 44) != (a[j - 1] >> 44)) ? 1 : 0;
  uniqueCnt[v] = u;
}

// ---------------- output offsets -------------------------------------------
// scal: 0=M1 1=M2 2=totSlots 3=E 4=facesOff 5=uvsOff 6=uvidxOff
__global__ void k_offsets(int* scal, int uvsElems) {
  int M1 = scal[0], M2 = scal[1], E = scal[3];
  int F = M1 + 2 * M2;
  scal[4] = 3 * E;
  scal[5] = 3 * E + 3 * F;
  scal[6] = scal[5] + uvsElems;
}

// ---------------- verts + per-occurrence rank (bucket-local dense writes) ----
__global__ void k_emit(const int* __restrict__ bucketOff, const int* __restrict__ bucketCnt,
                       const unsigned long long* __restrict__ edges, const int* __restrict__ uniqueOff,
                       const float* __restrict__ pos, const float* __restrict__ sdf,
                       int* __restrict__ rankArr, float* __restrict__ out, int nv) {
  int v = blockIdx.x * blockDim.x + threadIdx.x;
  if (v >= nv) return;
  int n = bucketCnt[v];
  if (n == 0) return;
  int off = bucketOff[v];
  int r = uniqueOff[v] - 1;
  unsigned long long prevHi = ~0ull;
  float s0 = sdf[v];
  float p0x = pos[3 * v], p0y = pos[3 * v + 1], p0z = pos[3 * v + 2];
  for (int j = 0; j < n; j++) {
    unsigned long long key = edges[off + j];
    unsigned long long hi44 = key >> 44;
    if (hi44 != prevHi) {
      prevHi = hi44;
      r++;
      int hi = (int)hi44;
      float s1 = sdf[hi];
      float ns1 = -s1;
      float denom = s0 + ns1;          // matches reference s.sum(1)
      float w0 = ns1 / denom;
      float w1 = s0 / denom;
      out[3 * r + 0] = p0x * w0 + pos[3 * hi + 0] * w1;
      out[3 * r + 1] = p0y * w0 + pos[3 * hi + 1] * w1;
      out[3 * r + 2] = p0z * w0 + pos[3 * hi + 2] * w1;
    }
    rankArr[off + (int)(key & 0xffffull)] = r;
  }
}

// ---------------- faces + uv_idx (dense writes, L3-resident rank gathers) ----
__global__ void k_face(const int4* __restrict__ tet, const uint8_t* __restrict__ tetidx,
                       const unsigned long long* __restrict__ tetRank, const int* __restrict__ scal,
                       const int* __restrict__ bucketOff, const ushort4* __restrict__ stash,
                       const int* __restrict__ rankArr, float* __restrict__ out, int nt) {
  int t = blockIdx.x * blockDim.x + threadIdx.x;
  if (t >= nt) return;
  int bits = tetidx[t];
  int nt3 = c_ntri[bits];
  if (nt3 == 0) return;
  int4 v = tet[t];
  int ids[4] = {v.x, v.y, v.z, v.w};
  ushort4 stv = stash[t];
  unsigned short sta[4] = {stv.x, stv.y, stv.z, stv.w};
  int rk[6];
  int c = 0;
#pragma unroll
  for (int e = 0; e < 6; e++) {
    int a = c_ea[e], b = c_eb[e];
    if ((((bits >> a) ^ (bits >> b)) & 1) == 0) continue;
    int va = ids[a], vb = ids[b];
    int lo = va < vb ? va : vb;
    rk[e] = rankArr[bucketOff[lo] + sta[c++]];
  }
  unsigned long long pk = tetRank[t];
  int M1 = scal[0], facesOff = scal[4], uvidxOff = scal[6];
  int row = (nt3 == 1) ? (int)(pk & 0xffffffffull) : M1 + 2 * (int)(pk >> 32);
  float* f = out + facesOff + (size_t)3 * row;
  int npos = 3 * nt3;
  for (int p = 0; p < npos; p++) f[p] = (float)rk[c_tri[bits][p]];
  float* o = out + uvidxOff + (size_t)3 * row;
  float bt4 = (float)(4 * t);
  o[0] = bt4; o[1] = bt4 + 1.0f; o[2] = bt4 + 2.0f;
  if (nt3 == 2) { o[3] = bt4; o[4] = bt4 + 2.0f; o[5] = bt4 + 3.0f; }
}

// ---------------- uvs --------------------------------------------------------
__global__ void k_uvs(const int* __restrict__ scal, float* __restrict__ out, int N) {
  int i = blockIdx.x * blockDim.x + threadIdx.x;
  int total = N * N;
  if (i >= total) return;
  int ty = i / N, tx = i - ty * N;
  float x = (float)tx / (float)N;
  float y = (float)ty / (float)N;
  float pad = (float)(0.9 / (double)N);
  float* o = out + scal[5] + (size_t)i * 8;
  o[0] = x;       o[1] = y;
  o[2] = x + pad; o[3] = y;
  o[4] = x + pad; o[5] = y + pad;
  o[6] = x;       o[7] = y + pad;
}

extern "C" void kernel_launch(void* const* d_in, const int* in_sizes, int n_in,
                              void* d_out, int out_size, void* d_ws, size_t ws_size,
                              hipStream_t stream) {
  const float* pos = (const float*)d_in[0];
  const float* sdf = (const float*)d_in[1];
  const int* tet = (const int*)d_in[2];
  int nv = in_sizes[1];
  int nt = in_sizes[2] / 4;

  // workspace layout (256B aligned slices)
  char* w = (char*)d_ws;
  size_t off = 0;
  auto A = [&](size_t bytes) -> char* {
    off = (off + 255) & ~(size_t)255;
    char* p = w + off;
    off += bytes;
    return p;
  };
  int* scal = (int*)A(64 * sizeof(int));
  uint8_t* tetidx = (uint8_t*)A((size_t)nt);
  unsigned long long* tetRank = (unsigned long long*)A((size_t)nt * 8);
  int* bucketCnt = (int*)A((size_t)nv * 4);
  int* bucketOff = (int*)A((size_t)nv * 4);
  int* uniqueCnt = (int*)A((size_t)nv * 4);
  int* uniqueOff = (int*)A((size_t)nv * 4);
  ushort4* stash = (ushort4*)A((size_t)nt * 8);
  int* rankArr = (int*)A((size_t)nt * 4 * 4);      // one int per possible occurrence
  unsigned long long* blockTotU = (unsigned long long*)A(8 * 4096);
  int* blockTotI = (int*)A(4 * 4096);
  unsigned long long* edges = (unsigned long long*)A((size_t)nt * 4 * 8); // <=4 crossing edges/tet

  hipMemsetAsync(bucketCnt, 0, (size_t)nv * 4, stream);

  int nb_t = (nt + SCHUNK - 1) / SCHUNK;
  int nb_v = (nv + SCHUNK - 1) / SCHUNK;

  k_classify<<<(nt + 255) / 256, 256, 0, stream>>>((const int4*)tet, sdf, tetidx, bucketCnt,
                                                   stash, nt);

  k_tetscan1<<<nb_t, SB, 0, stream>>>(tetidx, blockTotU, nt);
  k_scanblk_u64<<<1, SB, 0, stream>>>(blockTotU, nb_t, scal, 0, 1);
  k_tetscan3<<<nb_t, SB, 0, stream>>>(tetidx, blockTotU, tetRank, nt);

  k_i32scan1<<<nb_v, SB, 0, stream>>>(bucketCnt, blockTotI, nv);
  k_scanblk_i32<<<1, SB, 0, stream>>>(blockTotI, nb_v, scal, 2);
  k_i32scan3<<<nb_v, SB, 0, stream>>>(bucketCnt, blockTotI, bucketOff, nv);

  k_scatter<<<(nt + 255) / 256, 256, 0, stream>>>((const int4*)tet, tetidx, tetRank, scal,
                                                  bucketOff, stash, edges, nt);
  k_sortcnt<<<(nv + 255) / 256, 256, 0, stream>>>(bucketOff, bucketCnt, edges, uniqueCnt, nv);

  k_i32scan1<<<nb_v, SB, 0, stream>>>(uniqueCnt, blockTotI, nv);
  k_scanblk_i32<<<1, SB, 0, stream>>>(blockTotI, nb_v, scal, 3);
  k_i32scan3<<<nb_v, SB, 0, stream>>>(uniqueCnt, blockTotI, uniqueOff, nv);

  long long maxidx = (long long)nt * 2;
  int N = (int)ceil(sqrt((double)((maxidx + 1) / 2)));
  int uvsElems = N * N * 8;

  k_offsets<<<1, 1, 0, stream>>>(scal, uvsElems);
  k_emit<<<(nv + 255) / 256, 256, 0, stream>>>(bucketOff, bucketCnt, edges, uniqueOff,
                                               pos, sdf, rankArr, (float*)d_out, nv);
  k_face<<<(nt + 255) / 256, 256, 0, stream>>>((const int4*)tet, tetidx, tetRank, scal,
                                               bucketOff, stash, rankArr, (float*)d_out, nt);
  k_uvs<<<(N * N + 255) / 256, 256, 0, stream>>>(scal, (float*)d_out, N);
}

// Round 4
// 1036.802 us; speedup vs baseline: 2.0294x; 1.3290x over previous
//
#include <hip/hip_runtime.h>
#include <stdint.h>
#include <math.h>

#define SB 256
#define SI 8
#define SCHUNK (SB*SI)
#define SORT_LDS 8192   // u64 entries = 64 KB LDS per block (2 blocks/CU)

__constant__ int c_tri[16][6] = {
  {-1,-1,-1,-1,-1,-1},{1,0,2,-1,-1,-1},{4,0,3,-1,-1,-1},{1,4,2,1,3,4},
  {3,1,5,-1,-1,-1},{2,3,0,2,5,3},{1,4,0,1,5,4},{4,2,5,-1,-1,-1},
  {4,5,2,-1,-1,-1},{4,1,0,4,5,1},{3,2,0,3,5,2},{1,3,5,-1,-1,-1},
  {4,1,2,4,3,1},{3,0,4,-1,-1,-1},{2,0,1,-1,-1,-1},{-1,-1,-1,-1,-1,-1}};
__constant__ int c_ntri[16] = {0,1,1,2,1,2,2,1,1,2,2,1,2,1,1,0};
__constant__ int c_ea[6] = {0,0,0,1,1,2};
__constant__ int c_eb[6] = {1,2,3,2,3,3};

// ---------------- classify tets: occupancy bits + bucket count + slot stash --
__global__ void k_classify(const int4* __restrict__ tet, const float* __restrict__ sdf,
                           uint8_t* __restrict__ tetidx, int* __restrict__ bucketCnt,
                           ushort4* __restrict__ stash, int nt) {
  int t = blockIdx.x * blockDim.x + threadIdx.x;
  if (t >= nt) return;
  int4 v = tet[t];
  int ids[4] = {v.x, v.y, v.z, v.w};
  int bits = 0;
#pragma unroll
  for (int i = 0; i < 4; i++) bits |= (sdf[ids[i]] > 0.0f) ? (1 << i) : 0;
  tetidx[t] = (uint8_t)bits;
  if (c_ntri[bits] == 0) return;
  unsigned short st[4] = {0, 0, 0, 0};
  int c = 0;
#pragma unroll
  for (int e = 0; e < 6; e++) {
    int a = c_ea[e], b = c_eb[e];
    if ((((bits >> a) ^ (bits >> b)) & 1) == 0) continue;
    int va = ids[a], vb = ids[b];
    int lo = va < vb ? va : vb;
    st[c++] = (unsigned short)atomicAdd(&bucketCnt[lo], 1);
  }
  stash[t] = make_ushort4(st[0], st[1], st[2], st[3]);
}

// ---------------- block exclusive scans -------------------------------------
__device__ inline unsigned long long blkExclU64(unsigned long long val, unsigned long long* sh) {
  int tid = threadIdx.x;
  sh[tid] = val; __syncthreads();
  for (int st = 1; st < SB; st <<= 1) {
    unsigned long long add = (tid >= st) ? sh[tid - st] : 0ull;
    __syncthreads();
    sh[tid] += add;
    __syncthreads();
  }
  return sh[tid] - val;
}
__device__ inline int blkExclI32(int val, int* sh) {
  int tid = threadIdx.x;
  sh[tid] = val; __syncthreads();
  for (int st = 1; st < SB; st <<= 1) {
    int add = (tid >= st) ? sh[tid - st] : 0;
    __syncthreads();
    sh[tid] += add;
    __syncthreads();
  }
  return sh[tid] - val;
}

// tet scan: value = (ntri==1) | (ntri==2)<<32
__global__ void k_tetscan1(const uint8_t* __restrict__ tetidx, unsigned long long* __restrict__ bt, int n) {
  __shared__ unsigned long long sh[SB];
  int base = blockIdx.x * SCHUNK + threadIdx.x * SI;
  unsigned long long s = 0;
  for (int k = 0; k < SI; k++) {
    int i = base + k;
    if (i < n) {
      int nt3 = c_ntri[tetidx[i]];
      s += (nt3 == 1 ? 1ull : 0ull) + (nt3 == 2 ? (1ull << 32) : 0ull);
    }
  }
  sh[threadIdx.x] = s; __syncthreads();
  for (int st = SB / 2; st > 0; st >>= 1) {
    if (threadIdx.x < st) sh[threadIdx.x] += sh[threadIdx.x + st];
    __syncthreads();
  }
  if (threadIdx.x == 0) bt[blockIdx.x] = sh[0];
}

__global__ void k_scanblk_u64(unsigned long long* __restrict__ bt, int nb,
                              int* __restrict__ scal, int slotLo, int slotHi) {
  __shared__ unsigned long long sh[SB];
  __shared__ unsigned long long carrySh;
  if (threadIdx.x == 0) carrySh = 0;
  __syncthreads();
  for (int base = 0; base < nb; base += SB) {
    int i = base + threadIdx.x;
    unsigned long long v = (i < nb) ? bt[i] : 0ull;
    unsigned long long ex = blkExclU64(v, sh);
    unsigned long long carry = carrySh;
    if (i < nb) bt[i] = carry + ex;
    __syncthreads();
    if (threadIdx.x == SB - 1) carrySh = carry + ex + v;
    __syncthreads();
  }
  if (threadIdx.x == 0) {
    scal[slotLo] = (int)(carrySh & 0xffffffffull);
    scal[slotHi] = (int)(carrySh >> 32);
  }
}

__global__ void k_tetscan3(const uint8_t* __restrict__ tetidx, const unsigned long long* __restrict__ bt,
                           unsigned long long* __restrict__ tetRank, int n) {
  __shared__ unsigned long long sh[SB];
  int base = blockIdx.x * SCHUNK + threadIdx.x * SI;
  unsigned long long vals[SI];
  unsigned long long s = 0;
  for (int k = 0; k < SI; k++) {
    int i = base + k;
    unsigned long long v = 0;
    if (i < n) {
      int nt3 = c_ntri[tetidx[i]];
      v = (nt3 == 1 ? 1ull : 0ull) + (nt3 == 2 ? (1ull << 32) : 0ull);
    }
    vals[k] = s; s += v;
  }
  unsigned long long thrOff = blkExclU64(s, sh);
  unsigned long long off = bt[blockIdx.x] + thrOff;
  for (int k = 0; k < SI; k++) {
    int i = base + k;
    if (i < n) tetRank[i] = off + vals[k];
  }
}

__global__ void k_i32scan1(const int* __restrict__ src, int* __restrict__ bt, int n) {
  __shared__ int sh[SB];
  int base = blockIdx.x * SCHUNK + threadIdx.x * SI;
  int s = 0;
  for (int k = 0; k < SI; k++) { int i = base + k; if (i < n) s += src[i]; }
  sh[threadIdx.x] = s; __syncthreads();
  for (int st = SB / 2; st > 0; st >>= 1) {
    if (threadIdx.x < st) sh[threadIdx.x] += sh[threadIdx.x + st];
    __syncthreads();
  }
  if (threadIdx.x == 0) bt[blockIdx.x] = sh[0];
}

__global__ void k_scanblk_i32(int* __restrict__ bt, int nb, int* __restrict__ scal, int slot) {
  __shared__ int sh[SB];
  __shared__ int carrySh;
  if (threadIdx.x == 0) carrySh = 0;
  __syncthreads();
  for (int base = 0; base < nb; base += SB) {
    int i = base + threadIdx.x;
    int v = (i < nb) ? bt[i] : 0;
    int ex = blkExclI32(v, sh);
    int carry = carrySh;
    if (i < nb) bt[i] = carry + ex;
    __syncthreads();
    if (threadIdx.x == SB - 1) carrySh = carry + ex + v;
    __syncthreads();
  }
  if (threadIdx.x == 0) scal[slot] = carrySh;
}

__global__ void k_i32scan3(const int* __restrict__ src, const int* __restrict__ bt,
                           int* __restrict__ dst, int n) {
  __shared__ int sh[SB];
  int base = blockIdx.x * SCHUNK + threadIdx.x * SI;
  int vals[SI];
  int s = 0;
  for (int k = 0; k < SI; k++) {
    int i = base + k;
    int v = (i < n) ? src[i] : 0;
    vals[k] = s; s += v;
  }
  int thrOff = blkExclI32(s, sh);
  int off = bt[blockIdx.x] + thrOff;
  for (int k = 0; k < SI; k++) {
    int i = base + k;
    if (i < n) dst[i] = off + vals[k];
  }
}

// ---------------- scatter (atomic-free) --------------------------------------
// key: [63:44]=hi [43:20]=pos1 (face elem idx) [19:17]=delta [16]=has2 [15:0]=origIdxInBucket
__global__ void k_scatter(const int4* __restrict__ tet, const uint8_t* __restrict__ tetidx,
                          const unsigned long long* __restrict__ tetRank, const int* __restrict__ scal,
                          const int* __restrict__ bucketOff, const ushort4* __restrict__ stash,
                          unsigned long long* __restrict__ edges, int nt) {
  int t = blockIdx.x * blockDim.x + threadIdx.x;
  if (t >= nt) return;
  int bits = tetidx[t];
  int nt3 = c_ntri[bits];
  if (nt3 == 0) return;
  int4 v = tet[t];
  int ids[4] = {v.x, v.y, v.z, v.w};
  unsigned long long pk = tetRank[t];
  int M1 = scal[0];
  int rowElemBase = (nt3 == 1) ? 3 * (int)(pk & 0xffffffffull)
                               : 3 * M1 + 6 * (int)(pk >> 32);
  ushort4 stv = stash[t];
  unsigned short sta[4] = {stv.x, stv.y, stv.z, stv.w};
  int npos = 3 * nt3;
  int c = 0;
#pragma unroll
  for (int e = 0; e < 6; e++) {
    int a = c_ea[e], b = c_eb[e];
    if ((((bits >> a) ^ (bits >> b)) & 1) == 0) continue;
    int va = ids[a], vb = ids[b];
    int lo = va < vb ? va : vb;
    int hi = va < vb ? vb : va;
    int p1 = -1, p2 = -1;
    for (int p = 0; p < npos; p++) {
      if (c_tri[bits][p] == e) { if (p1 < 0) p1 = p; else p2 = p; }
    }
    int orig = sta[c++];
    unsigned long long key = ((unsigned long long)(unsigned)hi << 44)
                           | ((unsigned long long)(unsigned)(rowElemBase + p1) << 20)
                           | ((p2 >= 0) ? (((unsigned long long)(p2 - p1) << 17) | (1ull << 16)) : 0ull)
                           | (unsigned long long)orig;
    edges[bucketOff[lo] + orig] = key;
  }
}

// ---------------- per-bucket sort + unique count (LDS-staged) ----------------
// Block owns buckets [v0, v0+SB). Edge ranges of consecutive buckets are
// contiguous -> coalesced LDS load, in-LDS insertion sort, coalesced store.
// Fallback to global-memory sort if the block's range exceeds LDS (never for
// concentrated random data; correctness-only path).
__global__ __launch_bounds__(SB) void k_sortcnt(const int* __restrict__ bucketOff,
                          const int* __restrict__ bucketCnt,
                          unsigned long long* __restrict__ edges, int* __restrict__ uniqueCnt, int nv) {
  __shared__ unsigned long long sh[SORT_LDS];
  int v0 = blockIdx.x * SB;
  int vLast = v0 + SB - 1;
  if (vLast >= nv) vLast = nv - 1;
  int start = bucketOff[v0];
  int end = bucketOff[vLast] + bucketCnt[vLast];
  int cnt = end - start;
  int v = v0 + threadIdx.x;
  if (cnt <= SORT_LDS) {
    for (int i = threadIdx.x; i < cnt; i += SB) sh[i] = edges[start + i];
    __syncthreads();
    if (v < nv) {
      int n = bucketCnt[v];
      if (n == 0) { uniqueCnt[v] = 0; }
      else {
        unsigned long long* a = sh + (bucketOff[v] - start);
        for (int j = 1; j < n; j++) {
          unsigned long long key = a[j];
          int i = j - 1;
          while (i >= 0 && a[i] > key) { a[i + 1] = a[i]; i--; }
          a[i + 1] = key;
        }
        int u = 1;
        for (int j = 1; j < n; j++) u += ((a[j] >> 44) != (a[j - 1] >> 44)) ? 1 : 0;
        uniqueCnt[v] = u;
      }
    }
    __syncthreads();
    for (int i = threadIdx.x; i < cnt; i += SB) edges[start + i] = sh[i];
  } else {
    // correctness fallback: global-memory sort
    if (v < nv) {
      int n = bucketCnt[v];
      if (n == 0) { uniqueCnt[v] = 0; return; }
      unsigned long long* a = edges + bucketOff[v];
      for (int j = 1; j < n; j++) {
        unsigned long long key = a[j];
        int i = j - 1;
        while (i >= 0 && a[i] > key) { a[i + 1] = a[i]; i--; }
        a[i + 1] = key;
      }
      int u = 1;
      for (int j = 1; j < n; j++) u += ((a[j] >> 44) != (a[j - 1] >> 44)) ? 1 : 0;
      uniqueCnt[v] = u;
    }
  }
}

// ---------------- output offsets -------------------------------------------
// scal: 0=M1 1=M2 2=totSlots 3=E 4=facesOff 5=uvsOff 6=uvidxOff
__global__ void k_offsets(int* scal, int uvsElems) {
  int M1 = scal[0], M2 = scal[1], E = scal[3];
  int F = M1 + 2 * M2;
  scal[4] = 3 * E;
  scal[5] = 3 * E + 3 * F;
  scal[6] = scal[5] + uvsElems;
}

// ---------------- verts + per-occurrence rank (bucket-local dense writes) ----
__global__ void k_emit(const int* __restrict__ bucketOff, const int* __restrict__ bucketCnt,
                       const unsigned long long* __restrict__ edges, const int* __restrict__ uniqueOff,
                       const float* __restrict__ pos, const float* __restrict__ sdf,
                       int* __restrict__ rankArr, float* __restrict__ out, int nv) {
  int v = blockIdx.x * blockDim.x + threadIdx.x;
  if (v >= nv) return;
  int n = bucketCnt[v];
  if (n == 0) return;
  int off = bucketOff[v];
  int r = uniqueOff[v] - 1;
  unsigned long long prevHi = ~0ull;
  float s0 = sdf[v];
  float p0x = pos[3 * v], p0y = pos[3 * v + 1], p0z = pos[3 * v + 2];
  for (int j = 0; j < n; j++) {
    unsigned long long key = edges[off + j];
    unsigned long long hi44 = key >> 44;
    if (hi44 != prevHi) {
      prevHi = hi44;
      r++;
      int hi = (int)hi44;
      float s1 = sdf[hi];
      float ns1 = -s1;
      float denom = s0 + ns1;          // matches reference s.sum(1)
      float w0 = ns1 / denom;
      float w1 = s0 / denom;
      out[3 * r + 0] = p0x * w0 + pos[3 * hi + 0] * w1;
      out[3 * r + 1] = p0y * w0 + pos[3 * hi + 1] * w1;
      out[3 * r + 2] = p0z * w0 + pos[3 * hi + 2] * w1;
    }
    rankArr[off + (int)(key & 0xffffull)] = r;
  }
}

// ---------------- faces + uv_idx (dense writes, L3-resident rank gathers) ----
__global__ void k_face(const int4* __restrict__ tet, const uint8_t* __restrict__ tetidx,
                       const unsigned long long* __restrict__ tetRank, const int* __restrict__ scal,
                       const int* __restrict__ bucketOff, const ushort4* __restrict__ stash,
                       const int* __restrict__ rankArr, float* __restrict__ out, int nt) {
  int t = blockIdx.x * blockDim.x + threadIdx.x;
  if (t >= nt) return;
  int bits = tetidx[t];
  int nt3 = c_ntri[bits];
  if (nt3 == 0) return;
  int4 v = tet[t];
  int ids[4] = {v.x, v.y, v.z, v.w};
  ushort4 stv = stash[t];
  unsigned short sta[4] = {stv.x, stv.y, stv.z, stv.w};
  int rk[6];
  int c = 0;
#pragma unroll
  for (int e = 0; e < 6; e++) {
    int a = c_ea[e], b = c_eb[e];
    if ((((bits >> a) ^ (bits >> b)) & 1) == 0) continue;
    int va = ids[a], vb = ids[b];
    int lo = va < vb ? va : vb;
    rk[e] = rankArr[bucketOff[lo] + sta[c++]];
  }
  unsigned long long pk = tetRank[t];
  int M1 = scal[0], facesOff = scal[4], uvidxOff = scal[6];
  int row = (nt3 == 1) ? (int)(pk & 0xffffffffull) : M1 + 2 * (int)(pk >> 32);
  float* f = out + facesOff + (size_t)3 * row;
  int npos = 3 * nt3;
  for (int p = 0; p < npos; p++) f[p] = (float)rk[c_tri[bits][p]];
  float* o = out + uvidxOff + (size_t)3 * row;
  float bt4 = (float)(4 * t);
  o[0] = bt4; o[1] = bt4 + 1.0f; o[2] = bt4 + 2.0f;
  if (nt3 == 2) { o[3] = bt4; o[4] = bt4 + 2.0f; o[5] = bt4 + 3.0f; }
}

// ---------------- uvs --------------------------------------------------------
__global__ void k_uvs(const int* __restrict__ scal, float* __restrict__ out, int N) {
  int i = blockIdx.x * blockDim.x + threadIdx.x;
  int total = N * N;
  if (i >= total) return;
  int ty = i / N, tx = i - ty * N;
  float x = (float)tx / (float)N;
  float y = (float)ty / (float)N;
  float pad = (float)(0.9 / (double)N);
  float* o = out + scal[5] + (size_t)i * 8;
  o[0] = x;       o[1] = y;
  o[2] = x + pad; o[3] = y;
  o[4] = x + pad; o[5] = y + pad;
  o[6] = x;       o[7] = y + pad;
}

extern "C" void kernel_launch(void* const* d_in, const int* in_sizes, int n_in,
                              void* d_out, int out_size, void* d_ws, size_t ws_size,
                              hipStream_t stream) {
  const float* pos = (const float*)d_in[0];
  const float* sdf = (const float*)d_in[1];
  const int* tet = (const int*)d_in[2];
  int nv = in_sizes[1];
  int nt = in_sizes[2] / 4;

  // workspace layout (256B aligned slices)
  char* w = (char*)d_ws;
  size_t off = 0;
  auto A = [&](size_t bytes) -> char* {
    off = (off + 255) & ~(size_t)255;
    char* p = w + off;
    off += bytes;
    return p;
  };
  int* scal = (int*)A(64 * sizeof(int));
  uint8_t* tetidx = (uint8_t*)A((size_t)nt);
  unsigned long long* tetRank = (unsigned long long*)A((size_t)nt * 8);
  int* bucketCnt = (int*)A((size_t)nv * 4);
  int* bucketOff = (int*)A((size_t)nv * 4);
  int* uniqueCnt = (int*)A((size_t)nv * 4);
  int* uniqueOff = (int*)A((size_t)nv * 4);
  ushort4* stash = (ushort4*)A((size_t)nt * 8);
  int* rankArr = (int*)A((size_t)nt * 4 * 4);      // one int per possible occurrence
  unsigned long long* blockTotU = (unsigned long long*)A(8 * 4096);
  int* blockTotI = (int*)A(4 * 4096);
  unsigned long long* edges = (unsigned long long*)A((size_t)nt * 4 * 8); // <=4 crossing edges/tet

  hipMemsetAsync(bucketCnt, 0, (size_t)nv * 4, stream);

  int nb_t = (nt + SCHUNK - 1) / SCHUNK;
  int nb_v = (nv + SCHUNK - 1) / SCHUNK;

  k_classify<<<(nt + 255) / 256, 256, 0, stream>>>((const int4*)tet, sdf, tetidx, bucketCnt,
                                                   stash, nt);

  k_tetscan1<<<nb_t, SB, 0, stream>>>(tetidx, blockTotU, nt);
  k_scanblk_u64<<<1, SB, 0, stream>>>(blockTotU, nb_t, scal, 0, 1);
  k_tetscan3<<<nb_t, SB, 0, stream>>>(tetidx, blockTotU, tetRank, nt);

  k_i32scan1<<<nb_v, SB, 0, stream>>>(bucketCnt, blockTotI, nv);
  k_scanblk_i32<<<1, SB, 0, stream>>>(blockTotI, nb_v, scal, 2);
  k_i32scan3<<<nb_v, SB, 0, stream>>>(bucketCnt, blockTotI, bucketOff, nv);

  k_scatter<<<(nt + 255) / 256, 256, 0, stream>>>((const int4*)tet, tetidx, tetRank, scal,
                                                  bucketOff, stash, edges, nt);
  k_sortcnt<<<(nv + SB - 1) / SB, SB, 0, stream>>>(bucketOff, bucketCnt, edges, uniqueCnt, nv);

  k_i32scan1<<<nb_v, SB, 0, stream>>>(uniqueCnt, blockTotI, nv);
  k_scanblk_i32<<<1, SB, 0, stream>>>(blockTotI, nb_v, scal, 3);
  k_i32scan3<<<nb_v, SB, 0, stream>>>(uniqueCnt, blockTotI, uniqueOff, nv);

  long long maxidx = (long long)nt * 2;
  int N = (int)ceil(sqrt((double)((maxidx + 1) / 2)));
  int uvsElems = N * N * 8;

  k_offsets<<<1, 1, 0, stream>>>(scal, uvsElems);
  k_emit<<<(nv + 255) / 256, 256, 0, stream>>>(bucketOff, bucketCnt, edges, uniqueOff,
                                               pos, sdf, rankArr, (float*)d_out, nv);
  k_face<<<(nt + 255) / 256, 256, 0, stream>>>((const int4*)tet, tetidx, tetRank, scal,
                                               bucketOff, stash, rankArr, (float*)d_out, nt);
  k_uvs<<<(N * N + 255) / 256, 256, 0, stream>>>(scal, (float*)d_out, N);
}